// Round 8
// baseline (255.527 us; speedup 1.0000x reference)
//
#include <hip/hip_runtime.h>
#include <hip/hip_bf16.h>

// out[n] = b + e_x[n] * sum_m exp(2*GAMMA*dot(x_n,y_m)) * c[m]
// n=16384, m=8192, d=512.
// Round 8: BARRIER-FREE main loop. A (64 rows x 512k = 64KB) block-resident;
// B streamed WAVE-PRIVATE (each wave stages its own 64-col x 32-k chunk into
// its own 2x4KB dbuf via wave-scoped global_load_lds + counted vmcnt(4)).
// cw lives in LDS (no stray VMEM in the ledger). ZERO s_barrier after the
// prologue -> waves free-run; LDS pipe / MFMA pipe / epilogue VALU overlap
// across waves by HW scheduling (m114) instead of defeated source schedules.
// LDS: A 64KB @0 + B 8x8KB @65536 + cw 32KB @131072 = 160KB. 256 blocks (1/CU).
//
// Workspace: Xb bf16[16384*512] @0, Yb bf16[8192*512] @16777216,
//            ex f32[16384] @25165824, cw f32[8192] @25231360.

#define GAMMA 0.002f

typedef __bf16 bf16x8 __attribute__((ext_vector_type(8)));
typedef float  f32x4  __attribute__((ext_vector_type(4)));
typedef __attribute__((address_space(3))) void lds_void_t;
typedef __attribute__((address_space(1))) const void gl_void_t;

// ---------------- prep: f32 -> bf16 + exp(-gamma*||row||^2) (xW==nullptr)
// or c[m] = exp(-gamma*||row||^2)*W[m]
__global__ __launch_bounds__(256) void prep_kernel(const float* __restrict__ src,
                                                   __bf16* __restrict__ dst,
                                                   float* __restrict__ fac,
                                                   const float* __restrict__ xW,
                                                   int nrows) {
    const int wid  = threadIdx.x >> 6;
    const int lane = threadIdx.x & 63;
    const int row  = blockIdx.x * 4 + wid;
    if (row >= nrows) return;
    const float4* s = reinterpret_cast<const float4*>(src + (size_t)row * 512);
    float4 v0 = s[lane * 2];
    float4 v1 = s[lane * 2 + 1];
    float acc = v0.x * v0.x + v0.y * v0.y + v0.z * v0.z + v0.w * v0.w
              + v1.x * v1.x + v1.y * v1.y + v1.z * v1.z + v1.w * v1.w;
    bf16x8 o;
    o[0] = (__bf16)v0.x; o[1] = (__bf16)v0.y; o[2] = (__bf16)v0.z; o[3] = (__bf16)v0.w;
    o[4] = (__bf16)v1.x; o[5] = (__bf16)v1.y; o[6] = (__bf16)v1.z; o[7] = (__bf16)v1.w;
    *reinterpret_cast<bf16x8*>(dst + (size_t)row * 512 + lane * 8) = o;
#pragma unroll
    for (int off = 32; off >= 1; off >>= 1) acc += __shfl_xor(acc, off, 64);
    if (lane == 0) {
        float e = __expf(-GAMMA * acc);
        fac[row] = xW ? e * xW[row] : e;
    }
}

__global__ void init_out(float* __restrict__ out, const float* __restrict__ b, int n) {
    int i = blockIdx.x * blockDim.x + threadIdx.x;
    if (i < n) out[i] = b[0];
}

// ---------------- LDS geometry ----------------
// A @0: 16 kchunks(q) x 4 rowblocks(rb) x 1KB; within a 1KB block, k-major
//   granules (g = kslot*16 + row'): fragment read = block + lane*16 (r6-proven
//   conflict-free). Covers the block's 64 rows x 512 k.
// B @65536: wave wid region @ +wid*8192: 2 dbuf x 4KB; chunk = 4 colblocks x
//   1KB (16 cols x 32 k each), same k-major micro-layout. WAVE-PRIVATE.
// cw @131072: 8192 f32 (32KB), read-only after prologue.

// grid: 256 blocks (1/CU), 512 threads (8 waves); block = 64-row group x all cols.
__global__ __launch_bounds__(512, 2) void rbf_gemm(
    const __bf16* __restrict__ Xb, const __bf16* __restrict__ Yb,
    const float* __restrict__ ex, const float* __restrict__ cwp,
    float* __restrict__ out) {
    __shared__ __align__(128) char smem[163840];

    const int tid  = threadIdx.x;
    const int wid  = tid >> 6;
    const int lane = tid & 63;

    // XCD-contiguous row-group map: xcd owns 32 consecutive 64-row groups.
    const int pid = blockIdx.x;
    const int rg  = (pid & 7) * 32 + (pid >> 3);   // 0..255
    const int rowBase = rg * 64;

    const int l15 = lane & 15, l4 = lane >> 4;
    const int lane16 = lane * 16;
    const int bRegion = 65536 + wid * 8192;        // this wave's private B dbuf

    // per-lane global gather sources (k-major LDS layout, linear LDS dest)
    const __bf16* sAlane = Xb + (size_t)(rowBase + (wid & 3) * 16 + l15) * 512 + l4 * 8;
    const __bf16* sBlane = Yb + (size_t)(wid * 64 + l15) * 512 + l4 * 8;

    // ---- prologue: cw -> LDS, A panel -> LDS (cooperative), B chunk 0 (private)
#pragma unroll
    for (int i = 0; i < 4; ++i)
        __builtin_amdgcn_global_load_lds((gl_void_t*)(cwp + wid * 1024 + i * 256 + lane * 4),
            (lds_void_t*)(smem + 131072 + wid * 4096 + i * 1024), 16, 0, 0);
#pragma unroll
    for (int i = 0; i < 8; ++i) {
        const int q = (wid >> 2) * 8 + i;
        __builtin_amdgcn_global_load_lds((gl_void_t*)(sAlane + q * 32),
            (lds_void_t*)(smem + q * 4096 + (wid & 3) * 1024), 16, 0, 0);
    }
#pragma unroll
    for (int cb = 0; cb < 4; ++cb)
        __builtin_amdgcn_global_load_lds((gl_void_t*)(sBlane + cb * 8192),
            (lds_void_t*)(smem + bRegion + cb * 1024), 16, 0, 0);
    asm volatile("s_waitcnt vmcnt(0)");
    __builtin_amdgcn_s_barrier();          // the ONLY barrier

    f32x4 acc[4][4] = {};
    float rowsum[4][4] = {};
    const int lcol = l15, lrow = l4;

    // ---- main: 16 col-panels x 16 kchunks, NO barriers, wave-private vmcnt.
    for (int p = 0; p < 16; ++p) {
#pragma unroll
        for (int q = 0; q < 16; ++q) {
            const int c  = p * 16 + q;
            // stage chunk (c+1)&255 into the other private buffer
            const int q1 = (q + 1) & 15;
            const int p1 = (q == 15) ? ((p + 1) & 15) : p;
            const __bf16* src = sBlane + (size_t)p1 * 262144 + q1 * 32;
            const int dstb = bRegion + (((c + 1) & 1)) * 4096;
#pragma unroll
            for (int cb = 0; cb < 4; ++cb)
                __builtin_amdgcn_global_load_lds((gl_void_t*)(src + cb * 8192),
                    (lds_void_t*)(smem + dstb + cb * 1024), 16, 0, 0);

            asm volatile("s_waitcnt vmcnt(4)");   // chunk c landed; c+1 in flight
            __builtin_amdgcn_sched_barrier(0);    // pin ds_reads after the wait

            bf16x8 af[4], bfv[4];
#pragma unroll
            for (int rb = 0; rb < 4; ++rb)
                af[rb] = *reinterpret_cast<const bf16x8*>(
                    &smem[q * 4096 + rb * 1024 + lane16]);
#pragma unroll
            for (int cb = 0; cb < 4; ++cb)
                bfv[cb] = *reinterpret_cast<const bf16x8*>(
                    &smem[bRegion + (c & 1) * 4096 + cb * 1024 + lane16]);

            __builtin_amdgcn_s_setprio(1);
#pragma unroll
            for (int rb = 0; rb < 4; ++rb)
#pragma unroll
                for (int cb = 0; cb < 4; ++cb)
                    acc[rb][cb] = __builtin_amdgcn_mfma_f32_16x16x32_bf16(
                        af[rb], bfv[cb], acc[rb][cb], 0, 0, 0);
            __builtin_amdgcn_s_setprio(0);
        }

        // ---- per-panel epilogue (no barrier; cw from LDS, pure VALU otherwise)
        float cv[4];
#pragma unroll
        for (int cb = 0; cb < 4; ++cb)
            cv[cb] = *reinterpret_cast<const float*>(
                &smem[131072 + (p * 512 + wid * 64 + cb * 16 + lcol) * 4]);
#pragma unroll
        for (int rb = 0; rb < 4; ++rb)
#pragma unroll
            for (int i2 = 0; i2 < 4; ++i2) {
                float s = rowsum[rb][i2];
#pragma unroll
                for (int cb = 0; cb < 4; ++cb)
                    s += __expf(0.004f * acc[rb][cb][i2]) * cv[cb];
                rowsum[rb][i2] = s;
            }
#pragma unroll
        for (int rb = 0; rb < 4; ++rb)
#pragma unroll
            for (int cb = 0; cb < 4; ++cb)
                acc[rb][cb] = (f32x4){0.f, 0.f, 0.f, 0.f};
    }

    // ---- final: 16-lane reduce + one atomic per (wave, n); out pre-init'd to b
#pragma unroll
    for (int rb = 0; rb < 4; ++rb)
#pragma unroll
        for (int i2 = 0; i2 < 4; ++i2) {
            float s = rowsum[rb][i2];
#pragma unroll
            for (int off = 1; off < 16; off <<= 1) s += __shfl_xor(s, off, 64);
            if (lcol == 0) {
                const int n = rowBase + rb * 16 + lrow * 4 + i2;
                atomicAdd(&out[n], ex[n] * s);
            }
        }
}

extern "C" void kernel_launch(void* const* d_in, const int* in_sizes, int n_in,
                              void* d_out, int out_size, void* d_ws, size_t ws_size,
                              hipStream_t stream) {
    const float* X = (const float*)d_in[0];   // 16384 x 512
    const float* Y = (const float*)d_in[1];   //  8192 x 512
    const float* W = (const float*)d_in[2];   // 8192
    const float* b = (const float*)d_in[3];   // 1
    float* out = (float*)d_out;               // 16384

    char* ws = (char*)d_ws;
    __bf16* Xb = (__bf16*)(ws);
    __bf16* Yb = (__bf16*)(ws + 16777216);
    float*  ex = (float*)(ws + 16777216 + 8388608);
    float*  cw = (float*)(ws + 16777216 + 8388608 + 65536);

    prep_kernel<<<4096, 256, 0, stream>>>(X, Xb, ex, nullptr, 16384);
    prep_kernel<<<2048, 256, 0, stream>>>(Y, Yb, cw, W, 8192);
    init_out<<<64, 256, 0, stream>>>(out, b, 16384);
    rbf_gemm<<<256, 512, 0, stream>>>(Xb, Yb, ex, cw, out);
}

// Round 9
// 154.094 us; speedup vs baseline: 1.6583x; 1.6583x over previous
//
#include <hip/hip_runtime.h>
#include <hip/hip_bf16.h>

// out[n] = b + e_x[n] * sum_m exp(2*GAMMA*dot(x_n,y_m)) * c[m]
// n=16384, m=8192, d=512.
// Round 9: B-FROM-L2-REGISTERS + 2 blocks/CU. Y pre-transposed to MFMA
// fragment layout (Ybt[q][cb] 1KB blocks, lane off = lane*16B) -> wave loads
// B frags directly global->VGPR (one dwordx4, L2-hit). A (64r x 512k, k-major
// frag layout) + cw LDS-resident, read-only after ONE prologue barrier ->
// race-free, zero barriers/asm-waits in main loop. LDS 80KB -> 2 blocks/CU
// -> 4 waves/SIMD (2x latency hiding vs r5-r8). XCD keeps col-half L2-fit.
//
// Workspace: Xb bf16[16384*512] @0, Ybt bf16[8192*512] @16777216 (frag layout),
//            ex f32[16384] @25165824, cw f32[8192] @25231360.

#define GAMMA 0.002f

typedef __bf16 bf16x8 __attribute__((ext_vector_type(8)));
typedef float  f32x4  __attribute__((ext_vector_type(4)));
typedef __attribute__((address_space(3))) void lds_void_t;
typedef __attribute__((address_space(1))) const void gl_void_t;

// ---------------- prep X: f32 -> bf16 row-major + ex = exp(-g*||x||^2)
__global__ __launch_bounds__(256) void prep_x(const float* __restrict__ src,
                                              __bf16* __restrict__ dst,
                                              float* __restrict__ fac) {
    const int wid  = threadIdx.x >> 6;
    const int lane = threadIdx.x & 63;
    const int row  = blockIdx.x * 4 + wid;
    const float4* s = reinterpret_cast<const float4*>(src + (size_t)row * 512);
    float4 v0 = s[lane * 2];
    float4 v1 = s[lane * 2 + 1];
    float acc = v0.x * v0.x + v0.y * v0.y + v0.z * v0.z + v0.w * v0.w
              + v1.x * v1.x + v1.y * v1.y + v1.z * v1.z + v1.w * v1.w;
    bf16x8 o;
    o[0] = (__bf16)v0.x; o[1] = (__bf16)v0.y; o[2] = (__bf16)v0.z; o[3] = (__bf16)v0.w;
    o[4] = (__bf16)v1.x; o[5] = (__bf16)v1.y; o[6] = (__bf16)v1.z; o[7] = (__bf16)v1.w;
    *reinterpret_cast<bf16x8*>(dst + (size_t)row * 512 + lane * 8) = o;
#pragma unroll
    for (int off = 32; off >= 1; off >>= 1) acc += __shfl_xor(acc, off, 64);
    if (lane == 0) fac[row] = __expf(-GAMMA * acc);
}

// ---------------- prep Y: f32 -> bf16 FRAGMENT layout + cw = exp(-g*||y||^2)*W
// Ybt elem index for (m,k): q=k>>5, cb=m>>4, kslot=(k>>3)&3, col'=m&15:
//   ((q*512 + cb)*512) + (kslot*16 + col')*8 + (k&7)
// -> B-frag (q,cb) read = base + lane*8 elems (contiguous 1KB/wave).
__global__ __launch_bounds__(256) void prep_y(const float* __restrict__ src,
                                              __bf16* __restrict__ dst,
                                              float* __restrict__ fac,
                                              const float* __restrict__ W) {
    const int wid  = threadIdx.x >> 6;
    const int lane = threadIdx.x & 63;
    const int m    = blockIdx.x * 4 + wid;
    const float4* s = reinterpret_cast<const float4*>(src + (size_t)m * 512);
    float4 v0 = s[lane * 2];
    float4 v1 = s[lane * 2 + 1];
    float acc = v0.x * v0.x + v0.y * v0.y + v0.z * v0.z + v0.w * v0.w
              + v1.x * v1.x + v1.y * v1.y + v1.z * v1.z + v1.w * v1.w;
    bf16x8 o;
    o[0] = (__bf16)v0.x; o[1] = (__bf16)v0.y; o[2] = (__bf16)v0.z; o[3] = (__bf16)v0.w;
    o[4] = (__bf16)v1.x; o[5] = (__bf16)v1.y; o[6] = (__bf16)v1.z; o[7] = (__bf16)v1.w;
    const size_t idx = ((size_t)(lane >> 2) * 512 + (m >> 4)) * 512
                     + ((lane & 3) * 16 + (m & 15)) * 8;
    *reinterpret_cast<bf16x8*>(dst + idx) = o;
#pragma unroll
    for (int off = 32; off >= 1; off >>= 1) acc += __shfl_xor(acc, off, 64);
    if (lane == 0) fac[m] = __expf(-GAMMA * acc) * W[m];
}

__global__ void init_out(float* __restrict__ out, const float* __restrict__ b, int n) {
    int i = blockIdx.x * blockDim.x + threadIdx.x;
    if (i < n) out[i] = b[0];
}

// ---------------- LDS (80KB/block): A @0: [q 16][rb 4][1KB] k-major frag
// blocks (lane*16 read, conflict-free); cw @65536: 16KB (block's col-half).

#define LOADB(B, C) do { \
    const int q_ = (C) & 15, p_ = (C) >> 4; \
    const __bf16* bp_ = Ybt + ((size_t)q_ * 512 + cbgBase + p_ * 16) * 512 + lane8; \
    B[0] = *reinterpret_cast<const bf16x8*>(bp_); \
    B[1] = *reinterpret_cast<const bf16x8*>(bp_ + 512); \
} while (0)

#define READA(A, Q) do { \
    _Pragma("unroll") \
    for (int rb = 0; rb < 4; ++rb) \
        A[rb] = *reinterpret_cast<const bf16x8*>( \
            &smem[(Q) * 4096 + rb * 1024 + lane16]); \
} while (0)

#define MFMA8(A, B) do { \
    __builtin_amdgcn_s_setprio(1); \
    _Pragma("unroll") \
    for (int rb = 0; rb < 4; ++rb) \
        _Pragma("unroll") \
        for (int cb = 0; cb < 2; ++cb) \
            acc[rb][cb] = __builtin_amdgcn_mfma_f32_16x16x32_bf16( \
                A[rb], B[cb], acc[rb][cb], 0, 0, 0); \
    __builtin_amdgcn_s_setprio(0); \
} while (0)

// grid: 512 blocks (2/CU), 512 threads (8 waves = 8 col-eighths; tile 64x32/wave)
__global__ __launch_bounds__(512, 4) void rbf_gemm(
    const __bf16* __restrict__ Xb, const __bf16* __restrict__ Ybt,
    const float* __restrict__ ex, const float* __restrict__ cwp,
    float* __restrict__ out) {
    __shared__ __align__(128) char smem[81920];

    const int tid  = threadIdx.x;
    const int wid  = tid >> 6;           // = wc: col-eighth of each 256-col panel
    const int lane = tid & 63;

    // XCD map: even XCDs -> col-half 0, odd -> half 1; 64 blocks/XCD share one
    // 4MB Ybt half (L2-fit, r5-proven). rg = 64-row group, 0..255.
    const int pid = blockIdx.x;
    const int xcd = pid & 7;
    const int j   = pid >> 3;                    // 0..63
    const int ch  = xcd & 1;
    const int rg  = (xcd >> 1) * 64 + j;         // 0..255
    const int rowBase = rg * 64;
    const int colBase = ch * 4096;
    const int cbgBase = ch * 256 + wid * 2;      // global colblock base for this wave

    const int l15 = lane & 15, l4 = lane >> 4;
    const int lane16 = lane * 16;
    const int lane8  = lane * 8;

    // ---- prologue: A panel (64 blocks of 1KB, gather src) + cw -> LDS
#pragma unroll
    for (int i = 0; i < 8; ++i) {
        const int blk = wid * 8 + i;
        const int q = blk >> 2, rb = blk & 3;
        const __bf16* src = Xb + (size_t)(rowBase + rb * 16 + l15) * 512 + q * 32 + l4 * 8;
        __builtin_amdgcn_global_load_lds((gl_void_t*)src,
            (lds_void_t*)(smem + q * 4096 + rb * 1024), 16, 0, 0);
    }
#pragma unroll
    for (int i = 0; i < 2; ++i)
        __builtin_amdgcn_global_load_lds(
            (gl_void_t*)(cwp + colBase + wid * 512 + i * 256 + lane * 4),
            (lds_void_t*)(smem + 65536 + wid * 2048 + i * 1024), 16, 0, 0);
    asm volatile("s_waitcnt vmcnt(0)");
    __builtin_amdgcn_s_barrier();        // the only barrier; LDS read-only after

    f32x4 acc[4][2] = {};
    float rowsum[4][4] = {};

    bf16x8 A0[4], A1[4], B0[2], B1[2];
    LOADB(B0, 0);

    // ---- main: 256 iters (16 panels x 16 kchunks), no barriers, reg dbuf.
    for (int cc = 0; cc < 128; ++cc) {
        const int ce = 2 * cc, co = 2 * cc + 1;
        LOADB(B1, co);
        READA(A0, ce & 15);
        MFMA8(A0, B0);
        LOADB(B0, (co + 1) & 255);
        READA(A1, co & 15);
        MFMA8(A1, B1);
        if ((cc & 7) == 7) {
            // ---- per-panel epilogue: acc holds full K=512; pure VALU + LDS cw
            const int p = cc >> 3;
            float cv[2];
#pragma unroll
            for (int cb = 0; cb < 2; ++cb)
                cv[cb] = *reinterpret_cast<const float*>(
                    &smem[65536 + (p * 256 + wid * 32 + cb * 16 + l15) * 4]);
#pragma unroll
            for (int rb = 0; rb < 4; ++rb)
#pragma unroll
                for (int i2 = 0; i2 < 4; ++i2) {
                    rowsum[rb][i2] += __expf(0.004f * acc[rb][0][i2]) * cv[0]
                                    + __expf(0.004f * acc[rb][1][i2]) * cv[1];
                }
#pragma unroll
            for (int rb = 0; rb < 4; ++rb) {
                acc[rb][0] = (f32x4){0.f, 0.f, 0.f, 0.f};
                acc[rb][1] = (f32x4){0.f, 0.f, 0.f, 0.f};
            }
        }
    }

    // ---- final: 16-lane reduce + one atomic per (wave, n); out pre-init'd to b
#pragma unroll
    for (int rb = 0; rb < 4; ++rb)
#pragma unroll
        for (int i2 = 0; i2 < 4; ++i2) {
            float s = rowsum[rb][i2];
#pragma unroll
            for (int off = 1; off < 16; off <<= 1) s += __shfl_xor(s, off, 64);
            if (l15 == 0) {
                const int n = rowBase + rb * 16 + l4 * 4 + i2;
                atomicAdd(&out[n], ex[n] * s);
            }
        }
}

extern "C" void kernel_launch(void* const* d_in, const int* in_sizes, int n_in,
                              void* d_out, int out_size, void* d_ws, size_t ws_size,
                              hipStream_t stream) {
    const float* X = (const float*)d_in[0];   // 16384 x 512
    const float* Y = (const float*)d_in[1];   //  8192 x 512
    const float* W = (const float*)d_in[2];   // 8192
    const float* b = (const float*)d_in[3];   // 1
    float* out = (float*)d_out;               // 16384

    char* ws = (char*)d_ws;
    __bf16* Xb  = (__bf16*)(ws);
    __bf16* Ybt = (__bf16*)(ws + 16777216);
    float*  ex  = (float*)(ws + 16777216 + 8388608);
    float*  cw  = (float*)(ws + 16777216 + 8388608 + 65536);

    prep_x<<<4096, 256, 0, stream>>>(X, Xb, ex);
    prep_y<<<2048, 256, 0, stream>>>(Y, Ybt, cw, W);
    init_out<<<64, 256, 0, stream>>>(out, b, 16384);
    rbf_gemm<<<512, 512, 0, stream>>>(Xb, Ybt, ex, cw, out);
}

// Round 10
// 152.434 us; speedup vs baseline: 1.6763x; 1.0109x over previous
//
#include <hip/hip_runtime.h>
#include <hip/hip_bf16.h>

// out[n] = b + e_x[n] * sum_m exp(2*GAMMA*dot(x_n,y_m)) * c[m]
// n=16384, m=8192, d=512.
// Round 10: r9 structure (B-from-L2-registers, read-only LDS, zero main-loop
// barriers, 2 blocks/CU) with WAVE TILE WIDENED 64x32 -> 64x64: 16 MFMA per
// chunk against 4 A-ds_reads + 4 B-loads (halves LDS-read and VALU overhead
// per MFMA). 128 chunks (8 panels x 16 kchunks) per wave.
//
// Workspace: Xb bf16[16384*512] @0, Ybt bf16[8192*512] @16777216 (frag layout),
//            ex f32[16384] @25165824, cw f32[8192] @25231360.

#define GAMMA 0.002f

typedef __bf16 bf16x8 __attribute__((ext_vector_type(8)));
typedef float  f32x4  __attribute__((ext_vector_type(4)));
typedef __attribute__((address_space(3))) void lds_void_t;
typedef __attribute__((address_space(1))) const void gl_void_t;

// ---------------- prep X: f32 -> bf16 row-major + ex = exp(-g*||x||^2)
__global__ __launch_bounds__(256) void prep_x(const float* __restrict__ src,
                                              __bf16* __restrict__ dst,
                                              float* __restrict__ fac) {
    const int wid  = threadIdx.x >> 6;
    const int lane = threadIdx.x & 63;
    const int row  = blockIdx.x * 4 + wid;
    const float4* s = reinterpret_cast<const float4*>(src + (size_t)row * 512);
    float4 v0 = s[lane * 2];
    float4 v1 = s[lane * 2 + 1];
    float acc = v0.x * v0.x + v0.y * v0.y + v0.z * v0.z + v0.w * v0.w
              + v1.x * v1.x + v1.y * v1.y + v1.z * v1.z + v1.w * v1.w;
    bf16x8 o;
    o[0] = (__bf16)v0.x; o[1] = (__bf16)v0.y; o[2] = (__bf16)v0.z; o[3] = (__bf16)v0.w;
    o[4] = (__bf16)v1.x; o[5] = (__bf16)v1.y; o[6] = (__bf16)v1.z; o[7] = (__bf16)v1.w;
    *reinterpret_cast<bf16x8*>(dst + (size_t)row * 512 + lane * 8) = o;
#pragma unroll
    for (int off = 32; off >= 1; off >>= 1) acc += __shfl_xor(acc, off, 64);
    if (lane == 0) fac[row] = __expf(-GAMMA * acc);
}

// ---------------- prep Y: f32 -> bf16 FRAGMENT layout + cw = exp(-g*||y||^2)*W
// Ybt elem index for (m,k): q=k>>5, cb=m>>4, kslot=(k>>3)&3, col'=m&15:
//   ((q*512 + cb)*512) + (kslot*16 + col')*8 + (k&7)
// -> B-frag (q,cb) read = base + lane*8 elems (contiguous 1KB/wave).
__global__ __launch_bounds__(256) void prep_y(const float* __restrict__ src,
                                              __bf16* __restrict__ dst,
                                              float* __restrict__ fac,
                                              const float* __restrict__ W) {
    const int wid  = threadIdx.x >> 6;
    const int lane = threadIdx.x & 63;
    const int m    = blockIdx.x * 4 + wid;
    const float4* s = reinterpret_cast<const float4*>(src + (size_t)m * 512);
    float4 v0 = s[lane * 2];
    float4 v1 = s[lane * 2 + 1];
    float acc = v0.x * v0.x + v0.y * v0.y + v0.z * v0.z + v0.w * v0.w
              + v1.x * v1.x + v1.y * v1.y + v1.z * v1.z + v1.w * v1.w;
    bf16x8 o;
    o[0] = (__bf16)v0.x; o[1] = (__bf16)v0.y; o[2] = (__bf16)v0.z; o[3] = (__bf16)v0.w;
    o[4] = (__bf16)v1.x; o[5] = (__bf16)v1.y; o[6] = (__bf16)v1.z; o[7] = (__bf16)v1.w;
    const size_t idx = ((size_t)(lane >> 2) * 512 + (m >> 4)) * 512
                     + ((lane & 3) * 16 + (m & 15)) * 8;
    *reinterpret_cast<bf16x8*>(dst + idx) = o;
#pragma unroll
    for (int off = 32; off >= 1; off >>= 1) acc += __shfl_xor(acc, off, 64);
    if (lane == 0) fac[m] = __expf(-GAMMA * acc) * W[m];
}

__global__ void init_out(float* __restrict__ out, const float* __restrict__ b, int n) {
    int i = blockIdx.x * blockDim.x + threadIdx.x;
    if (i < n) out[i] = b[0];
}

// ---------------- LDS (80KB/block): A @0: [q 16][rb 4][1KB] k-major frag
// blocks (lane*16 read, conflict-free); cw @65536: 16KB (block's col-half).

// C = chunk 0..127: q = C&15, panel p = C>>4. Wave owns colblocks
// cbgBase + p*32 .. +3 (64 cols of the 512-col panel).
#define LOADB(B, C) do { \
    const int q_ = (C) & 15, p_ = (C) >> 4; \
    const __bf16* bp_ = Ybt + ((size_t)q_ * 512 + cbgBase + p_ * 32) * 512 + lane8; \
    B[0] = *reinterpret_cast<const bf16x8*>(bp_); \
    B[1] = *reinterpret_cast<const bf16x8*>(bp_ + 512); \
    B[2] = *reinterpret_cast<const bf16x8*>(bp_ + 1024); \
    B[3] = *reinterpret_cast<const bf16x8*>(bp_ + 1536); \
} while (0)

#define READA(A, Q) do { \
    _Pragma("unroll") \
    for (int rb = 0; rb < 4; ++rb) \
        A[rb] = *reinterpret_cast<const bf16x8*>( \
            &smem[(Q) * 4096 + rb * 1024 + lane16]); \
} while (0)

#define MFMA16(A, B) do { \
    __builtin_amdgcn_s_setprio(1); \
    _Pragma("unroll") \
    for (int rb = 0; rb < 4; ++rb) \
        _Pragma("unroll") \
        for (int cb = 0; cb < 4; ++cb) \
            acc[rb][cb] = __builtin_amdgcn_mfma_f32_16x16x32_bf16( \
                A[rb], B[cb], acc[rb][cb], 0, 0, 0); \
    __builtin_amdgcn_s_setprio(0); \
} while (0)

// grid: 512 blocks (2/CU), 512 threads (8 waves; wave tile 64 rows x 64 cols)
__global__ __launch_bounds__(512, 4) void rbf_gemm(
    const __bf16* __restrict__ Xb, const __bf16* __restrict__ Ybt,
    const float* __restrict__ ex, const float* __restrict__ cwp,
    float* __restrict__ out) {
    __shared__ __align__(128) char smem[81920];

    const int tid  = threadIdx.x;
    const int wid  = tid >> 6;
    const int lane = tid & 63;

    // XCD map (r9-proven): even XCDs -> col-half 0, odd -> 1; 64 blocks/XCD
    // share one 4MB Ybt half (L2-fit). rg = 64-row group.
    const int pid = blockIdx.x;
    const int xcd = pid & 7;
    const int j   = pid >> 3;                    // 0..63
    const int ch  = xcd & 1;
    const int rg  = (xcd >> 1) * 64 + j;         // 0..255
    const int rowBase = rg * 64;
    const int colBase = ch * 4096;
    const int cbgBase = ch * 256 + wid * 4;      // wave's colblock base per panel

    const int l15 = lane & 15, l4 = lane >> 4;
    const int lane16 = lane * 16;
    const int lane8  = lane * 8;

    // ---- prologue: A panel (64 x 1KB frag blocks, gather src) + cw -> LDS
#pragma unroll
    for (int i = 0; i < 8; ++i) {
        const int blk = wid * 8 + i;
        const int q = blk >> 2, rb = blk & 3;
        const __bf16* src = Xb + (size_t)(rowBase + rb * 16 + l15) * 512 + q * 32 + l4 * 8;
        __builtin_amdgcn_global_load_lds((gl_void_t*)src,
            (lds_void_t*)(smem + q * 4096 + rb * 1024), 16, 0, 0);
    }
#pragma unroll
    for (int i = 0; i < 2; ++i)
        __builtin_amdgcn_global_load_lds(
            (gl_void_t*)(cwp + colBase + wid * 512 + i * 256 + lane * 4),
            (lds_void_t*)(smem + 65536 + wid * 2048 + i * 1024), 16, 0, 0);
    asm volatile("s_waitcnt vmcnt(0)");
    __builtin_amdgcn_s_barrier();        // the only barrier; LDS read-only after

    f32x4 acc[4][4] = {};
    float rowsum[4][4] = {};

    bf16x8 A0[4], A1[4], B0[4], B1[4];
    LOADB(B0, 0);

    // ---- main: 128 chunks (8 panels x 16 kchunks), no barriers, reg dbuf.
    for (int cc = 0; cc < 64; ++cc) {
        const int ce = 2 * cc, co = 2 * cc + 1;
        LOADB(B1, co);
        READA(A0, ce & 15);
        MFMA16(A0, B0);
        LOADB(B0, (co + 1) & 127);
        READA(A1, co & 15);
        MFMA16(A1, B1);
        if ((cc & 7) == 7) {
            // ---- per-panel epilogue: acc holds full K=512; pure VALU + LDS cw
            const int p = cc >> 3;
            float cv[4];
#pragma unroll
            for (int cb = 0; cb < 4; ++cb)
                cv[cb] = *reinterpret_cast<const float*>(
                    &smem[65536 + (p * 512 + wid * 64 + cb * 16 + l15) * 4]);
#pragma unroll
            for (int rb = 0; rb < 4; ++rb)
#pragma unroll
                for (int i2 = 0; i2 < 4; ++i2) {
                    float s = rowsum[rb][i2];
#pragma unroll
                    for (int cb = 0; cb < 4; ++cb)
                        s += __expf(0.004f * acc[rb][cb][i2]) * cv[cb];
                    rowsum[rb][i2] = s;
                }
#pragma unroll
            for (int rb = 0; rb < 4; ++rb)
#pragma unroll
                for (int cb = 0; cb < 4; ++cb)
                    acc[rb][cb] = (f32x4){0.f, 0.f, 0.f, 0.f};
        }
    }

    // ---- final: 16-lane reduce + one atomic per (wave, n); out pre-init'd to b
#pragma unroll
    for (int rb = 0; rb < 4; ++rb)
#pragma unroll
        for (int i2 = 0; i2 < 4; ++i2) {
            float s = rowsum[rb][i2];
#pragma unroll
            for (int off = 1; off < 16; off <<= 1) s += __shfl_xor(s, off, 64);
            if (l15 == 0) {
                const int n = rowBase + rb * 16 + l4 * 4 + i2;
                atomicAdd(&out[n], ex[n] * s);
            }
        }
}

extern "C" void kernel_launch(void* const* d_in, const int* in_sizes, int n_in,
                              void* d_out, int out_size, void* d_ws, size_t ws_size,
                              hipStream_t stream) {
    const float* X = (const float*)d_in[0];   // 16384 x 512
    const float* Y = (const float*)d_in[1];   //  8192 x 512
    const float* W = (const float*)d_in[2];   // 8192
    const float* b = (const float*)d_in[3];   // 1
    float* out = (float*)d_out;               // 16384

    char* ws = (char*)d_ws;
    __bf16* Xb  = (__bf16*)(ws);
    __bf16* Ybt = (__bf16*)(ws + 16777216);
    float*  ex  = (float*)(ws + 16777216 + 8388608);
    float*  cw  = (float*)(ws + 16777216 + 8388608 + 65536);

    prep_x<<<4096, 256, 0, stream>>>(X, Xb, ex);
    prep_y<<<2048, 256, 0, stream>>>(Y, Ybt, cw, W);
    init_out<<<64, 256, 0, stream>>>(out, b, 16384);
    rbf_gemm<<<512, 512, 0, stream>>>(Xb, Ybt, ex, cw, out);
}